// Round 2
// baseline (760.176 us; speedup 1.0000x reference)
//
#include <hip/hip_runtime.h>
#include <cmath>

#define BATCH 8
#define CHN 256
#define HH 128
#define WW 128
#define HWSZ (HH*WW)
#define NCLS 81
#define NFG 80
#define KTOP 100
#define EPSV 1e-6f

typedef __attribute__((ext_vector_type(8))) short short8;
typedef __attribute__((ext_vector_type(4))) float f32x4;

__device__ __forceinline__ ushort f2bf(float f) {
    unsigned u = __float_as_uint(f);
    return (ushort)((u + 0x7FFFu + ((u >> 16) & 1u)) >> 16);
}
__device__ __forceinline__ float bf2f(ushort h) {
    return __uint_as_float(((unsigned)h) << 16);
}

// async global->LDS, 16B per lane; LDS dest is wave-uniform base + lane*16
__device__ __forceinline__ void gl16(const void* g, void* l) {
    __builtin_amdgcn_global_load_lds(
        (const __attribute__((address_space(1))) void*)g,
        (__attribute__((address_space(3))) void*)l, 16, 0, 0);
}

// ys scratch addressing: f32[32 rows][256 cols], 16B-unit XOR swizzle
// (c16 ^= row&15) -> conflict-free for b32 scatter writes AND b128 row reads.
__device__ __forceinline__ int ys_idx(int row, int col) {
    return row * 256 + ((((col >> 2) ^ row) & 15) << 2) + ((col >> 2) & ~15) * 4 + (col & 3);
}

// ===========================================================================
// prep_x: x NCHW fp32 -> xh/xl NHWC bf16 (hi + residual-lo). LDS transpose;
// phase-2 lanes write consecutive 16B channel chunks (contiguous 512B/px).
// ===========================================================================
__global__ __launch_bounds__(256) void prep_x(
    const float* __restrict__ x, ushort* __restrict__ xh, ushort* __restrict__ xl)
{
    __shared__ float tile[32][CHN + 1];    // [px][c]
    const int blk = blockIdx.x;            // 4096 = 8*128*4
    const int q4 = blk & 3, h = (blk >> 2) & 127, b = blk >> 9;
    const int w0 = q4 << 5;
    const int t = threadIdx.x;
    const int px1 = t & 31, cq = t >> 5;

    const float* xb = x + ((size_t)b * CHN) * HWSZ + h * WW + w0;
#pragma unroll 4
    for (int i = 0; i < 32; ++i) {
        int c = i * 8 + cq;
        tile[px1][c] = xb[(size_t)c * HWSZ + px1];
    }
    __syncthreads();
    for (int i = 0; i < 4; ++i) {
        int u = i * 256 + t;
        int c8 = u & 31, px = u >> 5;
        short8 hv, lv;
#pragma unroll
        for (int j = 0; j < 8; ++j) {
            float f = tile[px][c8 * 8 + j];
            ushort hb = f2bf(f);
            hv[j] = (short)hb;
            lv[j] = (short)f2bf(f - bf2f(hb));
        }
        size_t addr = ((size_t)b * HWSZ + h * WW + w0 + px) * CHN + c8 * 8;
        *(short8*)(xh + addr) = hv;
        *(short8*)(xl + addr) = lv;
    }
}

// ===========================================================================
// prep_w: w1 -> Bsw (conv B-frags, hi/lo), w2 -> w2sw (head B-frags, 96-oc pad)
// Bsw[(tap*8+kt)*16384 + spl*8192 + ntg*512 + lane*8 + j]
// w2sw[(kt*12 + spl*6 + ntg)*512 + lane*8 + j]
// ===========================================================================
__global__ __launch_bounds__(256) void prep_w(
    const float* __restrict__ w1, const float* __restrict__ w2,
    ushort* __restrict__ Bsw, ushort* __restrict__ w2sw)
{
    int i = blockIdx.x * 256 + threadIdx.x;     // 312*256 = 79872
    if (i < 73728) {                            // 9*8*16*64
        int tap  = i >> 13;
        int rem  = i & 8191;
        int kt   = rem >> 10;
        int rem2 = rem & 1023;
        int ntg  = rem2 >> 6;
        int lane = rem2 & 63;
        int oc   = ntg * 16 + (lane & 15);
        int ic0  = kt * 32 + (lane >> 4) * 8;
        size_t base = (size_t)(tap * 8 + kt) * 16384 + (size_t)ntg * 512 + lane * 8;
#pragma unroll
        for (int j = 0; j < 8; ++j) {
            float w  = w1[(size_t)oc * 2304 + (ic0 + j) * 9 + tap];
            ushort hb = f2bf(w);
            Bsw[base + j]        = hb;
            Bsw[base + 8192 + j] = f2bf(w - bf2f(hb));
        }
    } else {
        int j2 = i - 73728;                     // < 6144 = 8*2*6*64
        int kt   = j2 / 768;
        int rem  = j2 - kt * 768;
        int spl  = rem / 384;
        int rem2 = rem - spl * 384;
        int ntg  = rem2 >> 6;
        int lane = rem2 & 63;
        int oc   = ntg * 16 + (lane & 15);
        int ic0  = kt * 32 + (lane >> 4) * 8;
        size_t base = (size_t)(kt * 12 + spl * 6 + ntg) * 512 + lane * 8;
#pragma unroll
        for (int j = 0; j < 8; ++j) {
            float w = (oc < NCLS) ? w2[(size_t)oc * CHN + ic0 + j] : 0.f;
            ushort hb = f2bf(w);
            w2sw[base + j] = spl ? f2bf(w - bf2f(hb)) : hb;
        }
    }
}

// ===========================================================================
// conv3_fused: conv3x3 (row-pipelined, as proven in R1) + FUSED 1x1 head.
// Main loop identical to conv3_pipe. Epilogue: per 32-px chunk, relu(y) goes
// to swizzled LDS scratch (never to HBM), head MFMA (3-term split, same
// numerics as before), softmax/argmax, logits out. Eliminates the 268 MB
// y round-trip and the whole head_mfma kernel.
// ===========================================================================
__global__ __launch_bounds__(256, 2) void conv3_fused(
    const ushort* __restrict__ xh, const ushort* __restrict__ xl,
    const ushort* __restrict__ Bsw, const float* __restrict__ b1,
    const ushort* __restrict__ w2sw, const float* __restrict__ b2,
    float* __restrict__ logits_out, int* __restrict__ cls_map,
    float* __restrict__ prob_map)
{
    __shared__ union SMU {
        ushort A[3][2][132 * 32];                    // 50688 B (main loop)
        struct { float ys[32 * 256]; float ls[32 * 103]; } ep;  // 45952 B (epilogue)
    } sm;

    const int blk  = blockIdx.x;         // 1024 = 8*128
    const int b    = blk & 7;            // XCD-contiguous: each XCD owns one image
    const int h    = blk >> 3;
    const int t    = threadIdx.x;
    const int lane = t & 63;
    const int w    = t >> 6;             // wave: oc base = w*64
    const int l15  = lane & 15;
    const int q    = lane >> 4;

    // per-thread staging constants: 1024 16B units/phase = 128px x 4chunk x 2arr
    int colb[4], ldsu[4], basew[4];
#pragma unroll
    for (int r = 0; r < 4; ++r) {
        int e   = (r * 256 + t) & 511;
        int pxs = (e >> 2) + 1;
        int qq  = e & 3;
        int qs  = qq ^ ((pxs >> 1) & 3);          // pre-swizzled source chunk
        colb[r]  = (pxs - 1) * CHN + qs * 8;
        ldsu[r]  = pxs * 32 + qq * 8;             // linear dest (zero path)
        basew[r] = ((((r * 256 + (t & 192)) & 511) >> 2) + 1) * 32;  // wave base
    }

    const short8 zz = {0, 0, 0, 0, 0, 0, 0, 0};
    f32x4 acc[8][4];
#pragma unroll
    for (int i = 0; i < 8; ++i)
#pragma unroll
        for (int j = 0; j < 4; ++j) { f32x4 z = {0.f, 0.f, 0.f, 0.f}; acc[i][j] = z; }

    // one-time halo pre-zero: pxs in {0,129,130,131}, all slots/arrays/chunks
    if (t < 96) {
        int sl = t >> 5, rr = t & 31, arr = rr >> 4, pp = (rr >> 2) & 3, qq = rr & 3;
        int pxs = pp ? 128 + pp : 0;
        *(short8*)&sm.A[sl][arr][pxs * 32 + qq * 8] = zz;
    }

    auto stage = [&](int sn) {
        int kt1 = sn / 3;
        int kh1 = sn - kt1 * 3;                   // also the dest slot
        int gh  = h - 1 + kh1;
        if ((unsigned)gh < (unsigned)HH) {
            size_t rowb = ((size_t)(b * HH + gh) * WW) * CHN + kt1 * 32;
#pragma unroll
            for (int r = 0; r < 4; ++r) {
                const ushort* g = (r < 2 ? xh : xl) + rowb + colb[r];
                gl16(g, &sm.A[kh1][r >> 1][basew[r]]);
            }
        } else {
#pragma unroll
            for (int r = 0; r < 4; ++r)
                *(short8*)&sm.A[kh1][r >> 1][ldsu[r]] = zz;
        }
    };

    stage(0);
    __syncthreads();

#pragma unroll 1
    for (int s = 0; s < 24; ++s) {
        const int kt = s / 3;
        const int kh = s - kt * 3;                // current slot
#pragma unroll
        for (int kw = 0; kw < 3; ++kw) {
            const int tap = kh * 3 + kw;
            const ushort* bk = Bsw + (size_t)(tap * 8 + kt) * 16384 + lane * 8;
            short8 bh[4], bl[4];
#pragma unroll
            for (int nt = 0; nt < 4; ++nt) {
                bh[nt] = *(const short8*)(bk + (w * 4 + nt) * 512);
                bl[nt] = *(const short8*)(bk + 8192 + (w * 4 + nt) * 512);
            }
            if (kw == 0 && s < 23) stage(s + 1);
#pragma unroll
            for (int mth = 0; mth < 8; mth += 4) {
                short8 ahf[4], alf[4];
#pragma unroll
                for (int mm = 0; mm < 4; ++mm) {
                    int pxs = (mth + mm) * 16 + l15 + kw;
                    int cof = pxs * 32 + ((q ^ ((pxs >> 1) & 3)) * 8);  // swizzled read
                    ahf[mm] = *(const short8*)&sm.A[kh][0][cof];
                    alf[mm] = *(const short8*)&sm.A[kh][1][cof];
                }
                __builtin_amdgcn_s_setprio(1);
#pragma unroll
                for (int nt = 0; nt < 4; ++nt) {
#pragma unroll
                    for (int mm = 0; mm < 4; ++mm)
                        acc[mth + mm][nt] = __builtin_amdgcn_mfma_f32_16x16x32_bf16(
                            ahf[mm], bh[nt], acc[mth + mm][nt], 0, 0, 0);
#pragma unroll
                    for (int mm = 0; mm < 4; ++mm)
                        acc[mth + mm][nt] = __builtin_amdgcn_mfma_f32_16x16x32_bf16(
                            ahf[mm], bl[nt], acc[mth + mm][nt], 0, 0, 0);
#pragma unroll
                    for (int mm = 0; mm < 4; ++mm)
                        acc[mth + mm][nt] = __builtin_amdgcn_mfma_f32_16x16x32_bf16(
                            alf[mm], bh[nt], acc[mth + mm][nt], 0, 0, 0);
                }
                __builtin_amdgcn_s_setprio(0);
            }
        }
        __syncthreads();
    }

    // ===== fused head epilogue =====
    const size_t rowbase = (size_t)b * HWSZ + h * WW;
    const int mt2sel = w >> 1;          // 16-px subtile of the 32-px chunk
    const int ntb    = (w & 1) * 3;     // first of 3 head output tiles (nt)

    float b1c[4];
#pragma unroll
    for (int nt = 0; nt < 4; ++nt) b1c[nt] = b1[w * 64 + nt * 16 + l15];
    float b2c[3];
#pragma unroll
    for (int j = 0; j < 3; ++j) {
        int oc2 = (ntb + j) * 16 + l15;
        b2c[j] = (oc2 < NCLS) ? b2[oc2] : 0.f;
    }

    float* ys = sm.ep.ys;
    float* ls = sm.ep.ls;

#pragma unroll
    for (int p = 0; p < 4; ++p) {
        __syncthreads();
        // 1. relu(acc + b1) -> ys (swizzled, conflict-free)
#pragma unroll
        for (int h2 = 0; h2 < 2; ++h2) {
#pragma unroll
            for (int nt = 0; nt < 4; ++nt) {
                const int col = w * 64 + nt * 16 + l15;
#pragma unroll
                for (int r = 0; r < 4; ++r) {
                    const int row = h2 * 16 + q * 4 + r;
                    float v = acc[2 * p + h2][nt][r] + b1c[nt];
                    ys[ys_idx(row, col)] = v > 0.f ? v : 0.f;
                }
            }
        }
        __syncthreads();
        // 2. head MFMA: wave tile set = (mt2sel, ntb..ntb+2), 8 kt chunks
        f32x4 acc2[3];
#pragma unroll
        for (int j = 0; j < 3; ++j) { f32x4 z = {0.f, 0.f, 0.f, 0.f}; acc2[j] = z; }
        const int arow = mt2sel * 16 + l15;
#pragma unroll
        for (int kt = 0; kt < 8; ++kt) {
            const int c0 = kt * 32 + q * 8;
            float4 f0 = *(const float4*)&ys[arow * 256 + ((((c0 >> 2) ^ arow) & 15) << 2) + ((c0 >> 2) & ~15) * 4];
            const int c1 = c0 + 4;
            float4 f1 = *(const float4*)&ys[arow * 256 + ((((c1 >> 2) ^ arow) & 15) << 2) + ((c1 >> 2) & ~15) * 4];
            float fv[8] = {f0.x, f0.y, f0.z, f0.w, f1.x, f1.y, f1.z, f1.w};
            short8 ah, al;
#pragma unroll
            for (int j = 0; j < 8; ++j) {
                ushort hb = f2bf(fv[j]);
                ah[j] = (short)hb;
                al[j] = (short)f2bf(fv[j] - bf2f(hb));
            }
            const ushort* bk = w2sw + (size_t)kt * 12 * 512 + lane * 8;
#pragma unroll
            for (int j = 0; j < 3; ++j) {
                const int nt = ntb + j;
                short8 bh = *(const short8*)(bk + nt * 512);
                short8 bl = *(const short8*)(bk + (6 + nt) * 512);
                acc2[j] = __builtin_amdgcn_mfma_f32_16x16x32_bf16(ah, bh, acc2[j], 0, 0, 0);
                acc2[j] = __builtin_amdgcn_mfma_f32_16x16x32_bf16(ah, bl, acc2[j], 0, 0, 0);
                acc2[j] = __builtin_amdgcn_mfma_f32_16x16x32_bf16(al, bh, acc2[j], 0, 0, 0);
            }
        }
        // 3. logits + bias -> ls
#pragma unroll
        for (int j = 0; j < 3; ++j) {
            const int oc2 = (ntb + j) * 16 + l15;
#pragma unroll
            for (int r = 0; r < 4; ++r)
                ls[(mt2sel * 16 + q * 4 + r) * 103 + oc2] = acc2[j][r] + b2c[j];
        }
        __syncthreads();
        // 4. softmax + first-occurrence fg argmax (serial per px, exact same
        //    loop order as the old head_mfma -> bit-identical results)
        if (t < 32) {
            const int px = t;
            float m = -1e30f;
#pragma unroll
            for (int c = 0; c < NCLS; ++c) m = fmaxf(m, ls[px * 103 + c]);
            float s = 0.f;
            for (int c = 0; c < NCLS; ++c) s += expf(ls[px * 103 + c] - m);
            float best = -1e30f; int bc = 0;
            for (int c = 0; c < NFG; ++c) {
                float v = ls[px * 103 + c];
                if (v > best) { best = v; bc = c; }
            }
            cls_map[rowbase + p * 32 + px]  = bc;
            prob_map[rowbase + p * 32 + px] = expf(best - m) / s;
        }
        // logits out (NCHW), 128B rows
        for (int i = t; i < NCLS * 32; i += 256) {
            int c = i >> 5, pxl = i & 31;
            logits_out[((size_t)b * NCLS + c) * HWSZ + h * WW + p * 32 + pxl] = ls[pxl * 103 + c];
        }
    }
}

// ===========================================================================
// locmax (proven)
// ===========================================================================
__global__ __launch_bounds__(256) void locmax_kernel(
    const int* __restrict__ cls_map, const float* __restrict__ prob_map,
    float* __restrict__ score)
{
    int i = blockIdx.x * 256 + threadIdx.x;
    int b = i >> 14;
    int p = i & (HWSZ - 1);
    int h = p >> 7, w = p & 127;
    int mycls = cls_map[i];
    float myp = prob_map[i];
    bool lm = (myp >= EPSV);
#pragma unroll
    for (int dh = -1; dh <= 1; ++dh)
#pragma unroll
        for (int dw = -1; dw <= 1; ++dw) {
            if (dh == 0 && dw == 0) continue;
            int nh = h + dh, nw = w + dw;
            if ((unsigned)nh < HH && (unsigned)nw < WW) {
                int ni = b * HWSZ + nh * WW + nw;
                if (cls_map[ni] == mycls && myp < prob_map[ni]) lm = false;
            }
        }
    score[i] = myp + (lm ? 1.f : 0.f);
}

// ===========================================================================
// topk: 4-level byte-histogram radix select + rank scatter.
// jax.lax.top_k semantics: value desc, tie -> lower index (u64 (key<<32)|~p).
// Scores strictly positive -> float bits order-isomorphic.
// ===========================================================================
__global__ __launch_bounds__(1024) void topk_kernel(
    const float* __restrict__ score, int* __restrict__ idx_out)
{
    __shared__ unsigned int hist[256];
    __shared__ unsigned long long cand[2048];   // [0..127]: >K, [128..]: ==K
    __shared__ unsigned int sprefix, sneed, scntA, scntB;
    const int b = blockIdx.x;
    const int t = threadIdx.x;
    const float* sc = score + b * HWSZ;

    unsigned keys[16];
#pragma unroll
    for (int i = 0; i < 16; ++i)
        keys[i] = __float_as_uint(sc[t + (i << 10)]);

    if (t == 0) { sneed = KTOP; sprefix = 0; scntA = 0; scntB = 0; }

    for (int lvl = 0; lvl < 4; ++lvl) {
        const int shift = 24 - 8 * lvl;
        if (t < 256) hist[t] = 0;
        __syncthreads();
        const unsigned pref = sprefix;
#pragma unroll
        for (int i = 0; i < 16; ++i) {
            unsigned k = keys[i];
            bool match = (lvl == 0) || ((k >> (shift + 8)) == pref);
            if (match) atomicAdd(&hist[(k >> shift) & 255u], 1u);
        }
        __syncthreads();
        if (t == 0) {
            unsigned needv = sneed, c = 0; int bsel = 0;
            for (int j = 255; j >= 0; --j) {
                unsigned nc = c + hist[j];
                if (nc >= needv) { bsel = j; break; }
                c = nc;
            }
            sprefix = (pref << 8) | (unsigned)bsel;
            sneed = needv - c;
        }
        __syncthreads();
    }

    const unsigned K = sprefix;
#pragma unroll
    for (int i = 0; i < 16; ++i) {
        unsigned k = keys[i];
        int p = t + (i << 10);
        if (k > K) {
            unsigned pos = atomicAdd(&scntA, 1u);   // <= 99 guaranteed
            cand[pos] = ((unsigned long long)k << 32) | (unsigned)(~p);
        } else if (k == K) {
            unsigned pos = atomicAdd(&scntB, 1u);
            if (pos < 1920u)
                cand[128 + pos] = ((unsigned long long)k << 32) | (unsigned)(~p);
        }
    }
    __syncthreads();
    const int cA = (int)scntA;
    const int cB = (int)(scntB < 1920u ? scntB : 1920u);
    const int Ctot = cA + cB;
    for (int ti = t; ti < Ctot; ti += 1024) {
        unsigned long long my = cand[ti < cA ? ti : 128 + (ti - cA)];
        int rank = 0;
        for (int j = 0; j < Ctot; ++j) {
            unsigned long long o = cand[j < cA ? j : 128 + (j - cA)];
            rank += (o > my) ? 1 : 0;
        }
        if (rank < KTOP)
            idx_out[b * KTOP + rank] =
                (int)(~(unsigned)(my & 0xFFFFFFFFull)) & (HWSZ - 1);
    }
}

// ===========================================================================
// gather (proven)
// ===========================================================================
__global__ __launch_bounds__(256) void gather_kernel(
    const float* __restrict__ x, const float* __restrict__ pos,
    const int* __restrict__ idx, float* __restrict__ out0,
    float* __restrict__ out1)
{
    int blk = blockIdx.x;
    int b = blk / KTOP;
    int j = blk - b * KTOP;
    int c = threadIdx.x;
    int pix = idx[b * KTOP + j];
    out0[((size_t)b * CHN + c) * KTOP + j] = x[((size_t)b * CHN + c) * HWSZ + pix];
    out1[((size_t)b * CHN + c) * KTOP + j] = pos[(size_t)c * HWSZ + pix];
}

extern "C" void kernel_launch(void* const* d_in, const int* in_sizes, int n_in,
                              void* d_out, int out_size, void* d_ws, size_t ws_size,
                              hipStream_t stream) {
    (void)in_sizes; (void)n_in; (void)out_size; (void)ws_size;
    const float* x   = (const float*)d_in[0];
    const float* pos = (const float*)d_in[1];
    const float* w1  = (const float*)d_in[2];
    const float* b1  = (const float*)d_in[3];
    const float* w2  = (const float*)d_in[4];
    const float* b2  = (const float*)d_in[5];

    float* out0   = (float*)d_out;                    // [8,256,100]
    float* out1   = out0 + BATCH * CHN * KTOP;        // [8,256,100]
    float* logits = out1 + BATCH * CHN * KTOP;        // [8,81,128,128]

    char* ws = (char*)d_ws;
    const size_t NPX = (size_t)BATCH * HWSZ;          // 131072

    size_t off = 0;
    int*    cls_map  = (int*)(ws + off);    off += NPX * 4;
    float*  prob_map = (float*)(ws + off);  off += NPX * 4;
    float*  score    = (float*)(ws + off);  off += NPX * 4;
    int*    idx      = (int*)(ws + off);    off += 4096;
    ushort* w2sw     = (ushort*)(ws + off); off += (size_t)8 * 12 * 512 * 2;
    ushort* Bsw      = (ushort*)(ws + off); off += (size_t)9 * 8 * 16384 * 2;
    ushort* xh       = (ushort*)(ws + off); off += NPX * CHN * 2;
    ushort* xl       = (ushort*)(ws + off); off += NPX * CHN * 2;

    prep_x<<<4096, 256, 0, stream>>>(x, xh, xl);
    prep_w<<<312, 256, 0, stream>>>(w1, w2, Bsw, w2sw);
    conv3_fused<<<1024, 256, 0, stream>>>(xh, xl, Bsw, b1, w2sw, b2,
                                          logits, cls_map, prob_map);
    locmax_kernel<<<(int)(NPX / 256), 256, 0, stream>>>(cls_map, prob_map, score);
    topk_kernel<<<BATCH, 1024, 0, stream>>>(score, idx);
    gather_kernel<<<BATCH * KTOP, 256, 0, stream>>>(x, pos, idx, out0, out1);
}

// Round 3
// 702.611 us; speedup vs baseline: 1.0819x; 1.0819x over previous
//
#include <hip/hip_runtime.h>
#include <cmath>

#define BATCH 8
#define CHN 256
#define HH 128
#define WW 128
#define HWSZ (HH*WW)
#define NCLS 81
#define NFG 80
#define KTOP 100
#define EPSV 1e-6f

typedef __attribute__((ext_vector_type(8))) short short8;
typedef __attribute__((ext_vector_type(4))) float f32x4;

__device__ __forceinline__ ushort f2bf(float f) {
    unsigned u = __float_as_uint(f);
    return (ushort)((u + 0x7FFFu + ((u >> 16) & 1u)) >> 16);
}
__device__ __forceinline__ float bf2f(ushort h) {
    return __uint_as_float(((unsigned)h) << 16);
}

// async global->LDS, 16B per lane; LDS dest is wave-uniform base + lane*16
__device__ __forceinline__ void gl16(const void* g, void* l) {
    __builtin_amdgcn_global_load_lds(
        (const __attribute__((address_space(1))) void*)g,
        (__attribute__((address_space(3))) void*)l, 16, 0, 0);
}

// ===========================================================================
// prep_x: x NCHW fp32 -> xh/xl NHWC bf16 (hi + residual-lo). LDS transpose.
// Tile layout: [px][chunk c8][8] with 10-float chunk stride, 321-float row
// stride -> both write (px fast) and read (c8 fast) phases are <=2-way (free).
// ===========================================================================
__global__ __launch_bounds__(256) void prep_x(
    const float* __restrict__ x, ushort* __restrict__ xh, ushort* __restrict__ xl)
{
    __shared__ float tile[32 * 321];       // 41088 B
    const int blk = blockIdx.x;            // 4096 = 8*128*4
    const int q4 = blk & 3, h = (blk >> 2) & 127, b = blk >> 9;
    const int w0 = q4 << 5;
    const int t = threadIdx.x;
    const int px1 = t & 31, cq = t >> 5;

    const float* xb = x + ((size_t)b * CHN) * HWSZ + h * WW + w0;
#pragma unroll 4
    for (int i = 0; i < 32; ++i) {
        // c = i*8 + cq  -> chunk i, lane offset cq
        tile[px1 * 321 + i * 10 + cq] = xb[(size_t)(i * 8 + cq) * HWSZ + px1];
    }
    __syncthreads();
    for (int i = 0; i < 4; ++i) {
        int u = i * 256 + t;
        int c8 = u & 31, px = u >> 5;
        short8 hv, lv;
#pragma unroll
        for (int j = 0; j < 8; ++j) {
            float f = tile[px * 321 + c8 * 10 + j];
            ushort hb = f2bf(f);
            hv[j] = (short)hb;
            lv[j] = (short)f2bf(f - bf2f(hb));
        }
        size_t addr = ((size_t)b * HWSZ + h * WW + w0 + px) * CHN + c8 * 8;
        *(short8*)(xh + addr) = hv;
        *(short8*)(xl + addr) = lv;
    }
}

// ===========================================================================
// prep_w: w1 -> Bsw (conv B-frags, hi/lo), w2 -> w2sw (head B-frags, 96-oc pad)
// Bsw[(tap*8+kt)*16384 + spl*8192 + ntg*512 + lane*8 + j]
// w2sw[(kt*12 + spl*6 + ntg)*512 + lane*8 + j]
// ===========================================================================
__global__ __launch_bounds__(256) void prep_w(
    const float* __restrict__ w1, const float* __restrict__ w2,
    ushort* __restrict__ Bsw, ushort* __restrict__ w2sw)
{
    int i = blockIdx.x * 256 + threadIdx.x;     // 312*256 = 79872
    if (i < 73728) {                            // 9*8*16*64
        int tap  = i >> 13;
        int rem  = i & 8191;
        int kt   = rem >> 10;
        int rem2 = rem & 1023;
        int ntg  = rem2 >> 6;
        int lane = rem2 & 63;
        int oc   = ntg * 16 + (lane & 15);
        int ic0  = kt * 32 + (lane >> 4) * 8;
        size_t base = (size_t)(tap * 8 + kt) * 16384 + (size_t)ntg * 512 + lane * 8;
#pragma unroll
        for (int j = 0; j < 8; ++j) {
            float w  = w1[(size_t)oc * 2304 + (ic0 + j) * 9 + tap];
            ushort hb = f2bf(w);
            Bsw[base + j]        = hb;
            Bsw[base + 8192 + j] = f2bf(w - bf2f(hb));
        }
    } else {
        int j2 = i - 73728;                     // < 6144 = 8*2*6*64
        int kt   = j2 / 768;
        int rem  = j2 - kt * 768;
        int spl  = rem / 384;
        int rem2 = rem - spl * 384;
        int ntg  = rem2 >> 6;
        int lane = rem2 & 63;
        int oc   = ntg * 16 + (lane & 15);
        int ic0  = kt * 32 + (lane >> 4) * 8;
        size_t base = (size_t)(kt * 12 + spl * 6 + ntg) * 512 + lane * 8;
#pragma unroll
        for (int j = 0; j < 8; ++j) {
            float w = (oc < NCLS) ? w2[(size_t)oc * CHN + ic0 + j] : 0.f;
            ushort hb = f2bf(w);
            w2sw[base + j] = spl ? f2bf(w - bf2f(hb)) : hb;
        }
    }
}

// ===========================================================================
// conv3_pipe v2: block = one row (128 px) x 256 oc, 4 waves (128px x 64oc).
// 24 row-phases (8 kt x 3 kh), 3-slot circular LDS buffer (slot = kh).
// NEW vs R1: stage TWO rows ahead; phase-entry sync is counted
// s_waitcnt vmcnt(4) + raw s_barrier (never drains the newest prefetch).
// Boundary rows (h=0: slot0, h=127: slot2) are kt-invariant zeros -> zeroed
// ONCE up front; their stages are skipped and the entry wait drops to
// vmcnt(0) only on the phases whose next-stage was skipped.
// ===========================================================================
__global__ __launch_bounds__(256, 2) void conv3_pipe(
    const ushort* __restrict__ xh, const ushort* __restrict__ xl,
    const ushort* __restrict__ Bsw, const float* __restrict__ b1,
    float* __restrict__ y)
{
    __shared__ ushort A[3][2][132 * 32];   // [slot=kh][hi/lo][pxs*32 + ch], 50688 B

    const int blk  = blockIdx.x;         // 1024 = 8*128
    const int b    = blk & 7;            // XCD-contiguous: each XCD owns one image
    const int h    = blk >> 3;
    const int t    = threadIdx.x;
    const int lane = t & 63;
    const int w    = t >> 6;             // wave: oc base = w*64
    const int l15  = lane & 15;
    const int q    = lane >> 4;

    // per-thread staging constants: 1024 16B units/phase = 128px x 4chunk x 2arr
    int colb[4], basew[4];
#pragma unroll
    for (int r = 0; r < 4; ++r) {
        int e   = (r * 256 + t) & 511;
        int pxs = (e >> 2) + 1;
        int qq  = e & 3;
        int qs  = qq ^ ((pxs >> 1) & 3);          // pre-swizzled source chunk
        colb[r]  = (pxs - 1) * CHN + qs * 8;
        basew[r] = ((((r * 256 + (t & 192)) & 511) >> 2) + 1) * 32;  // wave base
    }

    const short8 zz = {0, 0, 0, 0, 0, 0, 0, 0};
    f32x4 acc[8][4];
#pragma unroll
    for (int i = 0; i < 8; ++i)
#pragma unroll
        for (int j = 0; j < 4; ++j) { f32x4 z = {0.f, 0.f, 0.f, 0.f}; acc[i][j] = z; }

    // one-time halo pre-zero: pxs in {0,129,130,131}, all slots/arrays/chunks
    if (t < 96) {
        int sl = t >> 5, rr = t & 31, arr = rr >> 4, pp = (rr >> 2) & 3, qq = rr & 3;
        int pxs = pp ? 128 + pp : 0;
        *(short8*)&A[sl][arr][pxs * 32 + qq * 8] = zz;
    }
    // boundary rows: whole slot is zero for every kt -> zero once, never stage
    if (h == 0 || h == 127) {
        const int sl = (h == 0) ? 0 : 2;
        for (int u = t; u < 1056; u += 256) {     // 2 arrays * 528 16B-units
            int arr = u >= 528; int v = arr ? u - 528 : u;
            *(short8*)&A[sl][arr][v * 8] = zz;
        }
    }

    auto stage = [&](int sn) {
        int kt1 = sn / 3;
        int kh1 = sn - kt1 * 3;                   // also the dest slot
        int gh  = h - 1 + kh1;
        if ((unsigned)gh < (unsigned)HH) {
            size_t rowb = ((size_t)(b * HH + gh) * WW) * CHN + kt1 * 32;
#pragma unroll
            for (int r = 0; r < 4; ++r) {
                const ushort* g = (r < 2 ? xh : xl) + rowb + colb[r];
                gl16(g, &A[kh1][r >> 1][basew[r]]);
            }
        }
    };

    stage(0);
    stage(1);

#pragma unroll 1
    for (int s = 0; s < 24; ++s) {
        const int kt = s / 3;
        const int kh = s - kt * 3;                // current slot
        // entry sync: stage(s) must have landed for all waves. Outstanding
        // (program order): stage(s) then stage(s+1) -> leave stage(s+1)'s
        // loads (4, or 0 if it was a skipped boundary row) in flight.
        {
            const int kh1n = (s + 1) % 3;
            const bool nx4 = (s < 23) &&
                !((h == 0 && kh1n == 0) || (h == 127 && kh1n == 2));
            if (nx4) asm volatile("s_waitcnt vmcnt(4) lgkmcnt(0)" ::: "memory");
            else     asm volatile("s_waitcnt vmcnt(0) lgkmcnt(0)" ::: "memory");
            __builtin_amdgcn_s_barrier();
            __builtin_amdgcn_sched_barrier(0);
        }
#pragma unroll
        for (int kw = 0; kw < 3; ++kw) {
            const int tap = kh * 3 + kw;
            const ushort* bk = Bsw + (size_t)(tap * 8 + kt) * 16384 + lane * 8;
            short8 bh[4], bl[4];
#pragma unroll
            for (int nt = 0; nt < 4; ++nt) {
                bh[nt] = *(const short8*)(bk + (w * 4 + nt) * 512);
                bl[nt] = *(const short8*)(bk + 8192 + (w * 4 + nt) * 512);
            }
            // issue stage(s+2) after tap0's B loads: slot (s+2)%3 was last
            // read in phase s-1 (all waves past the entry barrier), and the
            // loads get ~2 full phases in flight before their drain.
            if (kw == 0 && s < 22) stage(s + 2);
#pragma unroll
            for (int mth = 0; mth < 8; mth += 4) {
                short8 ahf[4], alf[4];
#pragma unroll
                for (int mm = 0; mm < 4; ++mm) {
                    int pxs = (mth + mm) * 16 + l15 + kw;
                    int cof = pxs * 32 + ((q ^ ((pxs >> 1) & 3)) * 8);  // swizzled read
                    ahf[mm] = *(const short8*)&A[kh][0][cof];
                    alf[mm] = *(const short8*)&A[kh][1][cof];
                }
                __builtin_amdgcn_s_setprio(1);
#pragma unroll
                for (int nt = 0; nt < 4; ++nt) {
#pragma unroll
                    for (int mm = 0; mm < 4; ++mm)
                        acc[mth + mm][nt] = __builtin_amdgcn_mfma_f32_16x16x32_bf16(
                            ahf[mm], bh[nt], acc[mth + mm][nt], 0, 0, 0);
#pragma unroll
                    for (int mm = 0; mm < 4; ++mm)
                        acc[mth + mm][nt] = __builtin_amdgcn_mfma_f32_16x16x32_bf16(
                            ahf[mm], bl[nt], acc[mth + mm][nt], 0, 0, 0);
#pragma unroll
                    for (int mm = 0; mm < 4; ++mm)
                        acc[mth + mm][nt] = __builtin_amdgcn_mfma_f32_16x16x32_bf16(
                            alf[mm], bh[nt], acc[mth + mm][nt], 0, 0, 0);
                }
                __builtin_amdgcn_s_setprio(0);
            }
        }
    }

    // epilogue: px = mt*16 + q*4 + r, oc = w*64 + nt*16 + l15
    const size_t rowbase = (size_t)b * HWSZ + h * WW;
#pragma unroll
    for (int nt = 0; nt < 4; ++nt) {
        const int oc = w * 64 + nt * 16 + l15;
        const float bias = b1[oc];
#pragma unroll
        for (int mt = 0; mt < 8; ++mt) {
#pragma unroll
            for (int r = 0; r < 4; ++r) {
                const int px = mt * 16 + q * 4 + r;
                float v = acc[mt][nt][r] + bias;
                y[(rowbase + px) * CHN + oc] = v > 0.f ? v : 0.f;
            }
        }
    }
}

// ===========================================================================
// head_mfma v2: 1x1 conv (256->81, pad 96) via MFMA, on-the-fly bf16 split.
// NEW vs R1: 4-kt register prefetch window (statically indexed) so the
// per-kt load->split->MFMA chain no longer serializes HBM latency 8x.
// Numerics identical to R1.
// ===========================================================================
__global__ __launch_bounds__(256) void head_mfma(
    const float* __restrict__ y, const ushort* __restrict__ w2sw,
    const float* __restrict__ b2, float* __restrict__ logits_out,
    int* __restrict__ cls_map, float* __restrict__ prob_map)
{
    __shared__ float ls[128][97];        // [px][oc], pad 97 (conflict-free)
    const int blk = blockIdx.x;          // 1024
    const int b = blk >> 7, h = blk & 127;
    const int t = threadIdx.x, lane = t & 63, wm = t >> 6;
    const int l15 = lane & 15, q = lane >> 4;

    f32x4 acc[2][6];
#pragma unroll
    for (int i = 0; i < 2; ++i)
#pragma unroll
        for (int j = 0; j < 6; ++j) { f32x4 z = {0.f, 0.f, 0.f, 0.f}; acc[i][j] = z; }

    const size_t rowbase = (size_t)b * HWSZ + h * WW;
    const float* yb0 = y + (rowbase + wm * 32 + l15) * CHN + q * 8;
    const float* yb1 = yb0 + 16 * CHN;

    float4 fa[2][4], fb[2][4];           // 4-kt rolling window, static indexing
#pragma unroll
    for (int k = 0; k < 4; ++k) {
        fa[0][k] = *(const float4*)(yb0 + k * 32);
        fb[0][k] = *(const float4*)(yb0 + k * 32 + 4);
        fa[1][k] = *(const float4*)(yb1 + k * 32);
        fb[1][k] = *(const float4*)(yb1 + k * 32 + 4);
    }

#pragma unroll
    for (int kt = 0; kt < 8; ++kt) {
        const int sl = kt & 3;
        short8 ah[2], al[2];
#pragma unroll
        for (int mt = 0; mt < 2; ++mt) {
            float4 f0 = fa[mt][sl];
            float4 f1 = fb[mt][sl];
            float fv[8] = {f0.x, f0.y, f0.z, f0.w, f1.x, f1.y, f1.z, f1.w};
#pragma unroll
            for (int j = 0; j < 8; ++j) {
                ushort hb = f2bf(fv[j]);
                ah[mt][j] = (short)hb;
                al[mt][j] = (short)f2bf(fv[j] - bf2f(hb));
            }
        }
        if (kt < 4) {                    // refill slot for kt+4
            fa[0][sl] = *(const float4*)(yb0 + (kt + 4) * 32);
            fb[0][sl] = *(const float4*)(yb0 + (kt + 4) * 32 + 4);
            fa[1][sl] = *(const float4*)(yb1 + (kt + 4) * 32);
            fb[1][sl] = *(const float4*)(yb1 + (kt + 4) * 32 + 4);
        }
        const ushort* bk = w2sw + (size_t)kt * 12 * 512 + lane * 8;
#pragma unroll
        for (int nt = 0; nt < 6; ++nt) {
            short8 bh = *(const short8*)(bk + nt * 512);
            short8 bl = *(const short8*)(bk + (6 + nt) * 512);
#pragma unroll
            for (int mt = 0; mt < 2; ++mt) {
                acc[mt][nt] = __builtin_amdgcn_mfma_f32_16x16x32_bf16(ah[mt], bh, acc[mt][nt], 0, 0, 0);
                acc[mt][nt] = __builtin_amdgcn_mfma_f32_16x16x32_bf16(ah[mt], bl, acc[mt][nt], 0, 0, 0);
                acc[mt][nt] = __builtin_amdgcn_mfma_f32_16x16x32_bf16(al[mt], bh, acc[mt][nt], 0, 0, 0);
            }
        }
    }

    // bias + stash logits to LDS
#pragma unroll
    for (int nt = 0; nt < 6; ++nt) {
        const int oc = nt * 16 + l15;
        const float bias = (oc < NCLS) ? b2[oc] : 0.f;
#pragma unroll
        for (int mt = 0; mt < 2; ++mt) {
#pragma unroll
            for (int r = 0; r < 4; ++r) {
                const int px = wm * 32 + mt * 16 + q * 4 + r;
                ls[px][oc] = acc[mt][nt][r] + bias;
            }
        }
    }
    __syncthreads();

    // logits out (NCHW), coalesced
    for (int i = t; i < NCLS * 128; i += 256) {
        int c = i >> 7, px = i & 127;
        logits_out[((size_t)b * NCLS + c) * HWSZ + h * WW + px] = ls[px][c];
    }

    // softmax + first-occurrence foreground argmax
    if (t < 128) {
        const int px = t;
        float m = -1e30f;
#pragma unroll
        for (int c = 0; c < NCLS; ++c) m = fmaxf(m, ls[px][c]);
        float s = 0.f;
        for (int c = 0; c < NCLS; ++c) s += expf(ls[px][c] - m);
        float best = -1e30f; int bc = 0;
        for (int c = 0; c < NFG; ++c) {
            float v = ls[px][c];
            if (v > best) { best = v; bc = c; }   // strict > keeps first index
        }
        cls_map[rowbase + px]  = bc;
        prob_map[rowbase + px] = expf(best - m) / s;
    }
}

// ===========================================================================
// locmax (proven)
// ===========================================================================
__global__ __launch_bounds__(256) void locmax_kernel(
    const int* __restrict__ cls_map, const float* __restrict__ prob_map,
    float* __restrict__ score)
{
    int i = blockIdx.x * 256 + threadIdx.x;
    int b = i >> 14;
    int p = i & (HWSZ - 1);
    int h = p >> 7, w = p & 127;
    int mycls = cls_map[i];
    float myp = prob_map[i];
    bool lm = (myp >= EPSV);
#pragma unroll
    for (int dh = -1; dh <= 1; ++dh)
#pragma unroll
        for (int dw = -1; dw <= 1; ++dw) {
            if (dh == 0 && dw == 0) continue;
            int nh = h + dh, nw = w + dw;
            if ((unsigned)nh < HH && (unsigned)nw < WW) {
                int ni = b * HWSZ + nh * WW + nw;
                if (cls_map[ni] == mycls && myp < prob_map[ni]) lm = false;
            }
        }
    score[i] = myp + (lm ? 1.f : 0.f);
}

// ===========================================================================
// topk: 4-level byte-histogram radix select + rank scatter.
// jax.lax.top_k semantics: value desc, tie -> lower index (u64 (key<<32)|~p).
// Scores strictly positive -> float bits order-isomorphic.
// ===========================================================================
__global__ __launch_bounds__(1024) void topk_kernel(
    const float* __restrict__ score, int* __restrict__ idx_out)
{
    __shared__ unsigned int hist[256];
    __shared__ unsigned long long cand[2048];   // [0..127]: >K, [128..]: ==K
    __shared__ unsigned int sprefix, sneed, scntA, scntB;
    const int b = blockIdx.x;
    const int t = threadIdx.x;
    const float* sc = score + b * HWSZ;

    unsigned keys[16];
#pragma unroll
    for (int i = 0; i < 16; ++i)
        keys[i] = __float_as_uint(sc[t + (i << 10)]);

    if (t == 0) { sneed = KTOP; sprefix = 0; scntA = 0; scntB = 0; }

    for (int lvl = 0; lvl < 4; ++lvl) {
        const int shift = 24 - 8 * lvl;
        if (t < 256) hist[t] = 0;
        __syncthreads();
        const unsigned pref = sprefix;
#pragma unroll
        for (int i = 0; i < 16; ++i) {
            unsigned k = keys[i];
            bool match = (lvl == 0) || ((k >> (shift + 8)) == pref);
            if (match) atomicAdd(&hist[(k >> shift) & 255u], 1u);
        }
        __syncthreads();
        if (t == 0) {
            unsigned needv = sneed, c = 0; int bsel = 0;
            for (int j = 255; j >= 0; --j) {
                unsigned nc = c + hist[j];
                if (nc >= needv) { bsel = j; break; }
                c = nc;
            }
            sprefix = (pref << 8) | (unsigned)bsel;
            sneed = needv - c;
        }
        __syncthreads();
    }

    const unsigned K = sprefix;
#pragma unroll
    for (int i = 0; i < 16; ++i) {
        unsigned k = keys[i];
        int p = t + (i << 10);
        if (k > K) {
            unsigned pos = atomicAdd(&scntA, 1u);   // <= 99 guaranteed
            cand[pos] = ((unsigned long long)k << 32) | (unsigned)(~p);
        } else if (k == K) {
            unsigned pos = atomicAdd(&scntB, 1u);
            if (pos < 1920u)
                cand[128 + pos] = ((unsigned long long)k << 32) | (unsigned)(~p);
        }
    }
    __syncthreads();
    const int cA = (int)scntA;
    const int cB = (int)(scntB < 1920u ? scntB : 1920u);
    const int Ctot = cA + cB;
    for (int ti = t; ti < Ctot; ti += 1024) {
        unsigned long long my = cand[ti < cA ? ti : 128 + (ti - cA)];
        int rank = 0;
        for (int j = 0; j < Ctot; ++j) {
            unsigned long long o = cand[j < cA ? j : 128 + (j - cA)];
            rank += (o > my) ? 1 : 0;
        }
        if (rank < KTOP)
            idx_out[b * KTOP + rank] =
                (int)(~(unsigned)(my & 0xFFFFFFFFull)) & (HWSZ - 1);
    }
}

// ===========================================================================
// gather (proven)
// ===========================================================================
__global__ __launch_bounds__(256) void gather_kernel(
    const float* __restrict__ x, const float* __restrict__ pos,
    const int* __restrict__ idx, float* __restrict__ out0,
    float* __restrict__ out1)
{
    int blk = blockIdx.x;
    int b = blk / KTOP;
    int j = blk - b * KTOP;
    int c = threadIdx.x;
    int pix = idx[b * KTOP + j];
    out0[((size_t)b * CHN + c) * KTOP + j] = x[((size_t)b * CHN + c) * HWSZ + pix];
    out1[((size_t)b * CHN + c) * KTOP + j] = pos[(size_t)c * HWSZ + pix];
}

extern "C" void kernel_launch(void* const* d_in, const int* in_sizes, int n_in,
                              void* d_out, int out_size, void* d_ws, size_t ws_size,
                              hipStream_t stream) {
    (void)in_sizes; (void)n_in; (void)out_size; (void)ws_size;
    const float* x   = (const float*)d_in[0];
    const float* pos = (const float*)d_in[1];
    const float* w1  = (const float*)d_in[2];
    const float* b1  = (const float*)d_in[3];
    const float* w2  = (const float*)d_in[4];
    const float* b2  = (const float*)d_in[5];

    float* out0   = (float*)d_out;                    // [8,256,100]
    float* out1   = out0 + BATCH * CHN * KTOP;        // [8,256,100]
    float* logits = out1 + BATCH * CHN * KTOP;        // [8,81,128,128]

    char* ws = (char*)d_ws;
    const size_t NPX = (size_t)BATCH * HWSZ;          // 131072

    size_t off = 0;
    int*    cls_map  = (int*)(ws + off);    off += NPX * 4;
    float*  prob_map = (float*)(ws + off);  off += NPX * 4;
    float*  score    = (float*)(ws + off);  off += NPX * 4;
    int*    idx      = (int*)(ws + off);    off += 4096;
    ushort* w2sw     = (ushort*)(ws + off); off += (size_t)8 * 12 * 512 * 2;
    ushort* Bsw      = (ushort*)(ws + off); off += (size_t)9 * 8 * 16384 * 2;
    ushort* xh       = (ushort*)(ws + off); off += NPX * CHN * 2;
    ushort* xl       = (ushort*)(ws + off); off += NPX * CHN * 2;
    float*  y        = (float*)(ws + off);  off += NPX * CHN * 4;

    prep_x<<<4096, 256, 0, stream>>>(x, xh, xl);
    prep_w<<<312, 256, 0, stream>>>(w1, w2, Bsw, w2sw);
    conv3_pipe<<<1024, 256, 0, stream>>>(xh, xl, Bsw, b1, y);
    head_mfma<<<1024, 256, 0, stream>>>(y, w2sw, b2, logits, cls_map, prob_map);
    locmax_kernel<<<(int)(NPX / 256), 256, 0, stream>>>(cls_map, prob_map, score);
    topk_kernel<<<BATCH, 1024, 0, stream>>>(score, idx);
    gather_kernel<<<BATCH * KTOP, 256, 0, stream>>>(x, pos, idx, out0, out1);
}

// Round 4
// 664.419 us; speedup vs baseline: 1.1441x; 1.0575x over previous
//
#include <hip/hip_runtime.h>
#include <cmath>

#define BATCH 8
#define CHN 256
#define HH 128
#define WW 128
#define HWSZ (HH*WW)
#define NCLS 81
#define NFG 80
#define KTOP 100
#define EPSV 1e-6f

typedef __attribute__((ext_vector_type(8))) short short8;
typedef __attribute__((ext_vector_type(4))) float f32x4;

__device__ __forceinline__ ushort f2bf(float f) {
    unsigned u = __float_as_uint(f);
    return (ushort)((u + 0x7FFFu + ((u >> 16) & 1u)) >> 16);
}
__device__ __forceinline__ float bf2f(ushort h) {
    return __uint_as_float(((unsigned)h) << 16);
}

// async global->LDS, 16B per lane; LDS dest is wave-uniform base + lane*16
__device__ __forceinline__ void gl16(const void* g, void* l) {
    __builtin_amdgcn_global_load_lds(
        (const __attribute__((address_space(1))) void*)g,
        (__attribute__((address_space(3))) void*)l, 16, 0, 0);
}

// ===========================================================================
// prep_x: x NCHW fp32 -> xh/xl NHWC bf16 (hi + residual-lo). LDS transpose.
// Tile layout: [px][chunk c8][8] with 10-float chunk stride, 321-float row
// stride -> both write (px fast) and read (c8 fast) phases are <=2-way (free).
// ===========================================================================
__global__ __launch_bounds__(256) void prep_x(
    const float* __restrict__ x, ushort* __restrict__ xh, ushort* __restrict__ xl)
{
    __shared__ float tile[32 * 321];       // 41088 B
    const int blk = blockIdx.x;            // 4096 = 8*128*4
    const int q4 = blk & 3, h = (blk >> 2) & 127, b = blk >> 9;
    const int w0 = q4 << 5;
    const int t = threadIdx.x;
    const int px1 = t & 31, cq = t >> 5;

    const float* xb = x + ((size_t)b * CHN) * HWSZ + h * WW + w0;
#pragma unroll 4
    for (int i = 0; i < 32; ++i) {
        // c = i*8 + cq  -> chunk i, lane offset cq
        tile[px1 * 321 + i * 10 + cq] = xb[(size_t)(i * 8 + cq) * HWSZ + px1];
    }
    __syncthreads();
    for (int i = 0; i < 4; ++i) {
        int u = i * 256 + t;
        int c8 = u & 31, px = u >> 5;
        short8 hv, lv;
#pragma unroll
        for (int j = 0; j < 8; ++j) {
            float f = tile[px * 321 + c8 * 10 + j];
            ushort hb = f2bf(f);
            hv[j] = (short)hb;
            lv[j] = (short)f2bf(f - bf2f(hb));
        }
        size_t addr = ((size_t)b * HWSZ + h * WW + w0 + px) * CHN + c8 * 8;
        *(short8*)(xh + addr) = hv;
        *(short8*)(xl + addr) = lv;
    }
}

// ===========================================================================
// prep_w: w1 -> Bsw (conv B-frags, hi/lo), w2 -> w2sw (head B-frags, 96-oc pad)
// Bsw[(tap*8+kt)*16384 + spl*8192 + ntg*512 + lane*8 + j]
// w2sw[(kt*12 + spl*6 + ntg)*512 + lane*8 + j]
// ===========================================================================
__global__ __launch_bounds__(256) void prep_w(
    const float* __restrict__ w1, const float* __restrict__ w2,
    ushort* __restrict__ Bsw, ushort* __restrict__ w2sw)
{
    int i = blockIdx.x * 256 + threadIdx.x;     // 312*256 = 79872
    if (i < 73728) {                            // 9*8*16*64
        int tap  = i >> 13;
        int rem  = i & 8191;
        int kt   = rem >> 10;
        int rem2 = rem & 1023;
        int ntg  = rem2 >> 6;
        int lane = rem2 & 63;
        int oc   = ntg * 16 + (lane & 15);
        int ic0  = kt * 32 + (lane >> 4) * 8;
        size_t base = (size_t)(tap * 8 + kt) * 16384 + (size_t)ntg * 512 + lane * 8;
#pragma unroll
        for (int j = 0; j < 8; ++j) {
            float w  = w1[(size_t)oc * 2304 + (ic0 + j) * 9 + tap];
            ushort hb = f2bf(w);
            Bsw[base + j]        = hb;
            Bsw[base + 8192 + j] = f2bf(w - bf2f(hb));
        }
    } else {
        int j2 = i - 73728;                     // < 6144 = 8*2*6*64
        int kt   = j2 / 768;
        int rem  = j2 - kt * 768;
        int spl  = rem / 384;
        int rem2 = rem - spl * 384;
        int ntg  = rem2 >> 6;
        int lane = rem2 & 63;
        int oc   = ntg * 16 + (lane & 15);
        int ic0  = kt * 32 + (lane >> 4) * 8;
        size_t base = (size_t)(kt * 12 + spl * 6 + ntg) * 512 + lane * 8;
#pragma unroll
        for (int j = 0; j < 8; ++j) {
            float w = (oc < NCLS) ? w2[(size_t)oc * CHN + ic0 + j] : 0.f;
            ushort hb = f2bf(w);
            w2sw[base + j] = spl ? f2bf(w - bf2f(hb)) : hb;
        }
    }
}

// ===========================================================================
// conv3_pipe v3: same proven pipeline as R3 (3-slot buffer, 2-ahead stage,
// counted vmcnt + raw barrier). NEW: all LDS/global frag addresses hoisted --
// A-frag swizzle base depends only on (l15+kw) [algebra: (pxs>>1)&3 ==
// ((l15+kw)>>1)&3 since the mm*16 part contributes 0 to bits 1-2], so reads
// become base-pointer + compile-time offset:N. Cuts ~100 VALU inst/phase/wave
// (kernel is issue-bound: MFMA 67% + VALU 20% + LDS 7% of SIMD issue).
// ===========================================================================
__global__ __launch_bounds__(256, 2) void conv3_pipe(
    const ushort* __restrict__ xh, const ushort* __restrict__ xl,
    const ushort* __restrict__ Bsw, const float* __restrict__ b1,
    float* __restrict__ y)
{
    __shared__ ushort A[3][2][132 * 32];   // [slot=kh][hi/lo][pxs*32 + ch], 50688 B

    const int blk  = blockIdx.x;         // 1024 = 8*128
    const int b    = blk & 7;            // XCD-contiguous: each XCD owns one image
    const int h    = blk >> 3;
    const int t    = threadIdx.x;
    const int lane = t & 63;
    const int w    = t >> 6;             // wave: oc base = w*64
    const int l15  = lane & 15;
    const int q    = lane >> 4;

    // per-thread staging constants: 1024 16B units/phase = 128px x 4chunk x 2arr
    int colb[4], basew[4];
#pragma unroll
    for (int r = 0; r < 4; ++r) {
        int e   = (r * 256 + t) & 511;
        int pxs = (e >> 2) + 1;
        int qq  = e & 3;
        int qs  = qq ^ ((pxs >> 1) & 3);          // pre-swizzled source chunk
        colb[r]  = (pxs - 1) * CHN + qs * 8;
        basew[r] = ((((r * 256 + (t & 192)) & 511) >> 2) + 1) * 32;  // wave base
    }

    // hoisted A-frag byte bases: addr = A[kh][arr] + abase[kw] + (mth+mm)*1024
    int abase[3];
#pragma unroll
    for (int kw = 0; kw < 3; ++kw) {
        int p0 = l15 + kw;
        abase[kw] = p0 * 64 + ((q ^ ((p0 >> 1) & 3)) << 4);
    }

    const short8 zz = {0, 0, 0, 0, 0, 0, 0, 0};
    f32x4 acc[8][4];
#pragma unroll
    for (int i = 0; i < 8; ++i)
#pragma unroll
        for (int j = 0; j < 4; ++j) { f32x4 z = {0.f, 0.f, 0.f, 0.f}; acc[i][j] = z; }

    // one-time halo pre-zero: pxs in {0,129,130,131}, all slots/arrays/chunks
    if (t < 96) {
        int sl = t >> 5, rr = t & 31, arr = rr >> 4, pp = (rr >> 2) & 3, qq = rr & 3;
        int pxs = pp ? 128 + pp : 0;
        *(short8*)&A[sl][arr][pxs * 32 + qq * 8] = zz;
    }
    // boundary rows: whole slot is zero for every kt -> zero once, never stage
    if (h == 0 || h == 127) {
        const int sl = (h == 0) ? 0 : 2;
        for (int u = t; u < 1056; u += 256) {     // 2 arrays * 528 16B-units
            int arr = u >= 528; int v = arr ? u - 528 : u;
            *(short8*)&A[sl][arr][v * 8] = zz;
        }
    }

    auto stage = [&](int sn) {
        int kt1 = sn / 3;
        int kh1 = sn - kt1 * 3;                   // also the dest slot
        int gh  = h - 1 + kh1;
        if ((unsigned)gh < (unsigned)HH) {
            size_t rowb = ((size_t)(b * HH + gh) * WW) * CHN + kt1 * 32;
#pragma unroll
            for (int r = 0; r < 4; ++r) {
                const ushort* g = (r < 2 ? xh : xl) + rowb + colb[r];
                gl16(g, &A[kh1][r >> 1][basew[r]]);
            }
        }
    };

    stage(0);
    stage(1);

#pragma unroll 1
    for (int s = 0; s < 24; ++s) {
        const int kt = s / 3;
        const int kh = s - kt * 3;                // current slot
        // entry sync: stage(s) must have landed for all waves; leave
        // stage(s+1)'s loads (4, or 0 if skipped boundary row) in flight.
        {
            const int kh1n = (s + 1) % 3;
            const bool nx4 = (s < 23) &&
                !((h == 0 && kh1n == 0) || (h == 127 && kh1n == 2));
            if (nx4) asm volatile("s_waitcnt vmcnt(4) lgkmcnt(0)" ::: "memory");
            else     asm volatile("s_waitcnt vmcnt(0) lgkmcnt(0)" ::: "memory");
            __builtin_amdgcn_s_barrier();
            __builtin_amdgcn_sched_barrier(0);
        }
#pragma unroll
        for (int kw = 0; kw < 3; ++kw) {
            const int tap = kh * 3 + kw;
            const char* bkh = (const char*)Bsw +
                ((size_t)(tap * 8 + kt) << 15) + (w << 12) + (lane << 4);
            const char* bkl = bkh + 16384;
            short8 bh[4], bl[4];
#pragma unroll
            for (int nt = 0; nt < 4; ++nt) {
                bh[nt] = *(const short8*)(bkh + nt * 1024);
                bl[nt] = *(const short8*)(bkl + nt * 1024);
            }
            if (kw == 0 && s < 22) stage(s + 2);
            const char* pah = (const char*)&A[kh][0][0] + abase[kw];
            const char* pal = (const char*)&A[kh][1][0] + abase[kw];
#pragma unroll
            for (int mth = 0; mth < 8; mth += 4) {
                short8 ahf[4], alf[4];
#pragma unroll
                for (int mm = 0; mm < 4; ++mm) {
                    ahf[mm] = *(const short8*)(pah + (mth + mm) * 1024);
                    alf[mm] = *(const short8*)(pal + (mth + mm) * 1024);
                }
                __builtin_amdgcn_s_setprio(1);
#pragma unroll
                for (int nt = 0; nt < 4; ++nt) {
#pragma unroll
                    for (int mm = 0; mm < 4; ++mm)
                        acc[mth + mm][nt] = __builtin_amdgcn_mfma_f32_16x16x32_bf16(
                            ahf[mm], bh[nt], acc[mth + mm][nt], 0, 0, 0);
#pragma unroll
                    for (int mm = 0; mm < 4; ++mm)
                        acc[mth + mm][nt] = __builtin_amdgcn_mfma_f32_16x16x32_bf16(
                            ahf[mm], bl[nt], acc[mth + mm][nt], 0, 0, 0);
#pragma unroll
                    for (int mm = 0; mm < 4; ++mm)
                        acc[mth + mm][nt] = __builtin_amdgcn_mfma_f32_16x16x32_bf16(
                            alf[mm], bh[nt], acc[mth + mm][nt], 0, 0, 0);
                }
                __builtin_amdgcn_s_setprio(0);
            }
        }
    }

    // epilogue: px = mt*16 + q*4 + r, oc = w*64 + nt*16 + l15
    const size_t rowbase = (size_t)b * HWSZ + h * WW;
#pragma unroll
    for (int nt = 0; nt < 4; ++nt) {
        const int oc = w * 64 + nt * 16 + l15;
        const float bias = b1[oc];
#pragma unroll
        for (int mt = 0; mt < 8; ++mt) {
#pragma unroll
            for (int r = 0; r < 4; ++r) {
                const int px = mt * 16 + q * 4 + r;
                float v = acc[mt][nt][r] + bias;
                y[(rowbase + px) * CHN + oc] = v > 0.f ? v : 0.f;
            }
        }
    }
}

// ===========================================================================
// head_mfma v2: 1x1 conv (256->81, pad 96) via MFMA, on-the-fly bf16 split,
// 4-kt register prefetch window (statically indexed). Numerics as R1.
// ===========================================================================
__global__ __launch_bounds__(256) void head_mfma(
    const float* __restrict__ y, const ushort* __restrict__ w2sw,
    const float* __restrict__ b2, float* __restrict__ logits_out,
    int* __restrict__ cls_map, float* __restrict__ prob_map)
{
    __shared__ float ls[128][97];        // [px][oc], pad 97 (conflict-free)
    const int blk = blockIdx.x;          // 1024
    const int b = blk >> 7, h = blk & 127;
    const int t = threadIdx.x, lane = t & 63, wm = t >> 6;
    const int l15 = lane & 15, q = lane >> 4;

    f32x4 acc[2][6];
#pragma unroll
    for (int i = 0; i < 2; ++i)
#pragma unroll
        for (int j = 0; j < 6; ++j) { f32x4 z = {0.f, 0.f, 0.f, 0.f}; acc[i][j] = z; }

    const size_t rowbase = (size_t)b * HWSZ + h * WW;
    const float* yb0 = y + (rowbase + wm * 32 + l15) * CHN + q * 8;
    const float* yb1 = yb0 + 16 * CHN;

    float4 fa[2][4], fb[2][4];           // 4-kt rolling window, static indexing
#pragma unroll
    for (int k = 0; k < 4; ++k) {
        fa[0][k] = *(const float4*)(yb0 + k * 32);
        fb[0][k] = *(const float4*)(yb0 + k * 32 + 4);
        fa[1][k] = *(const float4*)(yb1 + k * 32);
        fb[1][k] = *(const float4*)(yb1 + k * 32 + 4);
    }

#pragma unroll
    for (int kt = 0; kt < 8; ++kt) {
        const int sl = kt & 3;
        short8 ah[2], al[2];
#pragma unroll
        for (int mt = 0; mt < 2; ++mt) {
            float4 f0 = fa[mt][sl];
            float4 f1 = fb[mt][sl];
            float fv[8] = {f0.x, f0.y, f0.z, f0.w, f1.x, f1.y, f1.z, f1.w};
#pragma unroll
            for (int j = 0; j < 8; ++j) {
                ushort hb = f2bf(fv[j]);
                ah[mt][j] = (short)hb;
                al[mt][j] = (short)f2bf(fv[j] - bf2f(hb));
            }
        }
        if (kt < 4) {                    // refill slot for kt+4
            fa[0][sl] = *(const float4*)(yb0 + (kt + 4) * 32);
            fb[0][sl] = *(const float4*)(yb0 + (kt + 4) * 32 + 4);
            fa[1][sl] = *(const float4*)(yb1 + (kt + 4) * 32);
            fb[1][sl] = *(const float4*)(yb1 + (kt + 4) * 32 + 4);
        }
        const ushort* bk = w2sw + (size_t)kt * 12 * 512 + lane * 8;
#pragma unroll
        for (int nt = 0; nt < 6; ++nt) {
            short8 bh = *(const short8*)(bk + nt * 512);
            short8 bl = *(const short8*)(bk + (6 + nt) * 512);
#pragma unroll
            for (int mt = 0; mt < 2; ++mt) {
                acc[mt][nt] = __builtin_amdgcn_mfma_f32_16x16x32_bf16(ah[mt], bh, acc[mt][nt], 0, 0, 0);
                acc[mt][nt] = __builtin_amdgcn_mfma_f32_16x16x32_bf16(ah[mt], bl, acc[mt][nt], 0, 0, 0);
                acc[mt][nt] = __builtin_amdgcn_mfma_f32_16x16x32_bf16(al[mt], bh, acc[mt][nt], 0, 0, 0);
            }
        }
    }

    // bias + stash logits to LDS
#pragma unroll
    for (int nt = 0; nt < 6; ++nt) {
        const int oc = nt * 16 + l15;
        const float bias = (oc < NCLS) ? b2[oc] : 0.f;
#pragma unroll
        for (int mt = 0; mt < 2; ++mt) {
#pragma unroll
            for (int r = 0; r < 4; ++r) {
                const int px = wm * 32 + mt * 16 + q * 4 + r;
                ls[px][oc] = acc[mt][nt][r] + bias;
            }
        }
    }
    __syncthreads();

    // logits out (NCHW), coalesced
    for (int i = t; i < NCLS * 128; i += 256) {
        int c = i >> 7, px = i & 127;
        logits_out[((size_t)b * NCLS + c) * HWSZ + h * WW + px] = ls[px][c];
    }

    // softmax + first-occurrence foreground argmax
    if (t < 128) {
        const int px = t;
        float m = -1e30f;
#pragma unroll
        for (int c = 0; c < NCLS; ++c) m = fmaxf(m, ls[px][c]);
        float s = 0.f;
        for (int c = 0; c < NCLS; ++c) s += expf(ls[px][c] - m);
        float best = -1e30f; int bc = 0;
        for (int c = 0; c < NFG; ++c) {
            float v = ls[px][c];
            if (v > best) { best = v; bc = c; }   // strict > keeps first index
        }
        cls_map[rowbase + px]  = bc;
        prob_map[rowbase + px] = expf(best - m) / s;
    }
}

// ===========================================================================
// locmax (proven)
// ===========================================================================
__global__ __launch_bounds__(256) void locmax_kernel(
    const int* __restrict__ cls_map, const float* __restrict__ prob_map,
    float* __restrict__ score)
{
    int i = blockIdx.x * 256 + threadIdx.x;
    int b = i >> 14;
    int p = i & (HWSZ - 1);
    int h = p >> 7, w = p & 127;
    int mycls = cls_map[i];
    float myp = prob_map[i];
    bool lm = (myp >= EPSV);
#pragma unroll
    for (int dh = -1; dh <= 1; ++dh)
#pragma unroll
        for (int dw = -1; dw <= 1; ++dw) {
            if (dh == 0 && dw == 0) continue;
            int nh = h + dh, nw = w + dw;
            if ((unsigned)nh < HH && (unsigned)nw < WW) {
                int ni = b * HWSZ + nh * WW + nw;
                if (cls_map[ni] == mycls && myp < prob_map[ni]) lm = false;
            }
        }
    score[i] = myp + (lm ? 1.f : 0.f);
}

// ===========================================================================
// topk: 4-level byte-histogram radix select + rank scatter.
// jax.lax.top_k semantics: value desc, tie -> lower index (u64 (key<<32)|~p).
// NEW: bin selection via parallel 8-step suffix scan (exact same integer
// semantics as the old serial t==0 scan: bsel = max j with suffix[j] >= need,
// sneed = need - suffix[bsel+1]).
// ===========================================================================
__global__ __launch_bounds__(1024) void topk_kernel(
    const float* __restrict__ score, int* __restrict__ idx_out)
{
    __shared__ unsigned int hist[256];
    __shared__ unsigned int suf[256];
    __shared__ unsigned long long cand[2048];   // [0..127]: >K, [128..]: ==K
    __shared__ unsigned int sprefix, sneed, scntA, scntB;
    const int b = blockIdx.x;
    const int t = threadIdx.x;
    const float* sc = score + b * HWSZ;

    unsigned keys[16];
#pragma unroll
    for (int i = 0; i < 16; ++i)
        keys[i] = __float_as_uint(sc[t + (i << 10)]);

    if (t == 0) { sneed = KTOP; sprefix = 0; scntA = 0; scntB = 0; }

    for (int lvl = 0; lvl < 4; ++lvl) {
        const int shift = 24 - 8 * lvl;
        if (t < 256) hist[t] = 0;
        __syncthreads();
        const unsigned pref = sprefix;
#pragma unroll
        for (int i = 0; i < 16; ++i) {
            unsigned k = keys[i];
            bool match = (lvl == 0) || ((k >> (shift + 8)) == pref);
            if (match) atomicAdd(&hist[(k >> shift) & 255u], 1u);
        }
        __syncthreads();
        // parallel suffix scan: suf[j] = sum_{k>=j} hist[k]
        if (t < 256) suf[t] = hist[t];
        __syncthreads();
#pragma unroll
        for (int st = 1; st < 256; st <<= 1) {
            unsigned v = 0;
            if (t < 256 && t + st < 256) v = suf[t + st];
            __syncthreads();
            if (t < 256) suf[t] += v;
            __syncthreads();
        }
        const unsigned needv = sneed;
        __syncthreads();
        if (t < 256) {
            unsigned sj  = suf[t];
            unsigned sj1 = (t == 255) ? 0u : suf[t + 1];
            if (sj >= needv && sj1 < needv) {     // unique winner
                sprefix = (pref << 8) | (unsigned)t;
                sneed   = needv - sj1;
            }
        }
        __syncthreads();
    }

    const unsigned K = sprefix;
#pragma unroll
    for (int i = 0; i < 16; ++i) {
        unsigned k = keys[i];
        int p = t + (i << 10);
        if (k > K) {
            unsigned pos = atomicAdd(&scntA, 1u);   // <= 99 guaranteed
            cand[pos] = ((unsigned long long)k << 32) | (unsigned)(~p);
        } else if (k == K) {
            unsigned pos = atomicAdd(&scntB, 1u);
            if (pos < 1920u)
                cand[128 + pos] = ((unsigned long long)k << 32) | (unsigned)(~p);
        }
    }
    __syncthreads();
    const int cA = (int)scntA;
    const int cB = (int)(scntB < 1920u ? scntB : 1920u);
    const int Ctot = cA + cB;
    for (int ti = t; ti < Ctot; ti += 1024) {
        unsigned long long my = cand[ti < cA ? ti : 128 + (ti - cA)];
        int rank = 0;
        for (int j = 0; j < Ctot; ++j) {
            unsigned long long o = cand[j < cA ? j : 128 + (j - cA)];
            rank += (o > my) ? 1 : 0;
        }
        if (rank < KTOP)
            idx_out[b * KTOP + rank] =
                (int)(~(unsigned)(my & 0xFFFFFFFFull)) & (HWSZ - 1);
    }
}

// ===========================================================================
// gather v2: one block per (b, c) -> writes fully coalesced (was 400B-stride
// scatter = ~26 MB HBM write for 1.6 MB logical). Reads stay inherent gather.
// ===========================================================================
__global__ __launch_bounds__(128) void gather_kernel(
    const float* __restrict__ x, const float* __restrict__ pos,
    const int* __restrict__ idx, float* __restrict__ out0,
    float* __restrict__ out1)
{
    int blk = blockIdx.x;                // 2048 = 8*256
    int b = blk >> 8, c = blk & 255;
    int j = threadIdx.x;
    if (j < KTOP) {
        int pix = idx[b * KTOP + j];
        out0[((size_t)b * CHN + c) * KTOP + j] = x[((size_t)b * CHN + c) * HWSZ + pix];
        out1[((size_t)b * CHN + c) * KTOP + j] = pos[(size_t)c * HWSZ + pix];
    }
}

extern "C" void kernel_launch(void* const* d_in, const int* in_sizes, int n_in,
                              void* d_out, int out_size, void* d_ws, size_t ws_size,
                              hipStream_t stream) {
    (void)in_sizes; (void)n_in; (void)out_size; (void)ws_size;
    const float* x   = (const float*)d_in[0];
    const float* pos = (const float*)d_in[1];
    const float* w1  = (const float*)d_in[2];
    const float* b1  = (const float*)d_in[3];
    const float* w2  = (const float*)d_in[4];
    const float* b2  = (const float*)d_in[5];

    float* out0   = (float*)d_out;                    // [8,256,100]
    float* out1   = out0 + BATCH * CHN * KTOP;        // [8,256,100]
    float* logits = out1 + BATCH * CHN * KTOP;        // [8,81,128,128]

    char* ws = (char*)d_ws;
    const size_t NPX = (size_t)BATCH * HWSZ;          // 131072

    size_t off = 0;
    int*    cls_map  = (int*)(ws + off);    off += NPX * 4;
    float*  prob_map = (float*)(ws + off);  off += NPX * 4;
    float*  score    = (float*)(ws + off);  off += NPX * 4;
    int*    idx      = (int*)(ws + off);    off += 4096;
    ushort* w2sw     = (ushort*)(ws + off); off += (size_t)8 * 12 * 512 * 2;
    ushort* Bsw      = (ushort*)(ws + off); off += (size_t)9 * 8 * 16384 * 2;
    ushort* xh       = (ushort*)(ws + off); off += NPX * CHN * 2;
    ushort* xl       = (ushort*)(ws + off); off += NPX * CHN * 2;
    float*  y        = (float*)(ws + off);  off += NPX * CHN * 4;

    prep_x<<<4096, 256, 0, stream>>>(x, xh, xl);
    prep_w<<<312, 256, 0, stream>>>(w1, w2, Bsw, w2sw);
    conv3_pipe<<<1024, 256, 0, stream>>>(xh, xl, Bsw, b1, y);
    head_mfma<<<1024, 256, 0, stream>>>(y, w2sw, b2, logits, cls_map, prob_map);
    locmax_kernel<<<(int)(NPX / 256), 256, 0, stream>>>(cls_map, prob_map, score);
    topk_kernel<<<BATCH, 1024, 0, stream>>>(score, idx);
    gather_kernel<<<BATCH * CHN, 128, 0, stream>>>(x, pos, idx, out0, out1);
}